// Round 8
// baseline (213.248 us; speedup 1.0000x reference)
//
#include <hip/hip_runtime.h>

typedef __bf16 bf16x8_t __attribute__((ext_vector_type(8)));
typedef float f32x16_t __attribute__((ext_vector_type(16)));
typedef unsigned short ushort_t;

__device__ __forceinline__ unsigned short f2bf(float f) {
  unsigned u = __float_as_uint(f);
  u = (u + 0x7FFFu + ((u >> 16) & 1u)) >> 16;
  return (unsigned short)u;
}
__device__ __forceinline__ float bf2f(unsigned short h) {
  return __uint_as_float(((unsigned)h) << 16);
}

// async global->LDS, 16B/lane. LDS dest = wave-uniform base + lane*16.
__device__ __forceinline__ void gload16(const void* g, void* l) {
  __builtin_amdgcn_global_load_lds(
      (const __attribute__((address_space(1))) unsigned int*)g,
      (__attribute__((address_space(3))) unsigned int*)l, 16, 0, 0);
}

#define SBAR()                              \
  do {                                      \
    __builtin_amdgcn_s_barrier();           \
    __builtin_amdgcn_sched_barrier(0);      \
  } while (0)
#define VMCNT(N)                                            \
  do {                                                      \
    asm volatile("s_waitcnt vmcnt(" #N ")" ::: "memory");   \
    __builtin_amdgcn_sched_barrier(0);                      \
  } while (0)

// ===========================================================================
// 128x128 NT GEMM, mfma_f32_32x32x16_bf16, **3-buffer counted-vmcnt pipeline**:
//   iter t: stage(t+2)->buf[(t+2)%3]; ds_read buf[t%3]; MFMA;
//           vmcnt(4)  [t+1 resident, t+2's 4 loads stay in flight]; s_barrier.
// Gives each staging load ~2 iterations (~1800cyc) vs HBM ~900cyc latency.
// Swizzle g(row)=(row>>1)&3 both-sides (src-preswizzled global + XOR ds_read).
// EPI: 0 = plain (+bias), 1 = exp()+row-partial-sums (softmax fused into S),
//      2 = scale rows by aux[row] (1/l applied in PV).
// C/D 32x32 layout: col=lane&31, row=(reg&3)+8*(reg>>2)+4*(lane>>5) [m74/m101]
// ===========================================================================
template<int EPI, bool OUT_BF16, bool HAS_BIAS>
__global__ __launch_bounds__(256, 3)
void gemm32(const ushort_t* __restrict__ A, const ushort_t* __restrict__ Bt,
            void* __restrict__ Cp, const float* __restrict__ bias,
            float* __restrict__ aux,
            int gx, int gy, int K, int lda, int ldb, int ldc,
            long sA, long sB, long sC, float alpha)
{
  __shared__ __align__(16) ushort_t sm[3 * 8192];  // 48KB: 3 buf x (A4096+B4096)
  const int tid = threadIdx.x;
  const int lane = tid & 63;
  const int w = tid >> 6;
  const int wr = w >> 1, wc = w & 1;

  // bijective XCD-chunked swizzle (grids %8==0)
  const int per = gridDim.x >> 3;
  int wg = blockIdx.x;
  wg = (wg & 7) * per + (wg >> 3);
  const int bz = wg / (gx * gy);
  const int rr = wg - bz * gx * gy;
  const int by = rr / gx, bx = rr - by * gx;
  const int bm = by * 128, bn = bx * 128;

  // staging ptrs (source pre-swizzled): slot q=w*2+i rows q*16+(lane>>2)
  const int r0 = (w * 2) * 16 + (lane >> 2);
  const int csw = (((lane & 3) ^ ((r0 >> 1) & 3)) << 3);
  const ushort_t* pA0 = A + (long)bz * sA + (long)(bm + r0) * lda + csw;
  const ushort_t* pA1 = pA0 + 16 * lda;
  const ushort_t* pB0 = Bt + (long)bz * sB + (long)(bn + r0) * ldb + csw;
  const ushort_t* pB1 = pB0 + 16 * ldb;

  auto stage = [&](int kt, int buf) {
    const int k0 = kt << 5;
    ushort_t* s = sm + buf * 8192;
    gload16(pA0 + k0, s + (w * 2) * 512);
    gload16(pA1 + k0, s + (w * 2 + 1) * 512);
    gload16(pB0 + k0, s + 4096 + (w * 2) * 512);
    gload16(pB1 + k0, s + 4096 + (w * 2 + 1) * 512);
  };

  // fragment ds_read offsets
  const int l31 = lane & 31, kh = lane >> 5;
  int offA[2][2], offB[2][2];
#pragma unroll
  for (int m = 0; m < 2; ++m) {
    const int row = wr * 64 + m * 32 + l31;
#pragma unroll
    for (int s = 0; s < 2; ++s)
      offA[m][s] = row * 32 + (((s * 2 + kh) ^ ((row >> 1) & 3)) << 3);
  }
#pragma unroll
  for (int n = 0; n < 2; ++n) {
    const int row = wc * 64 + n * 32 + l31;
#pragma unroll
    for (int s = 0; s < 2; ++s)
      offB[n][s] = 4096 + row * 32 + (((s * 2 + kh) ^ ((row >> 1) & 3)) << 3);
  }

  f32x16_t acc[2][2];
#pragma unroll
  for (int m = 0; m < 2; ++m)
#pragma unroll
    for (int n = 0; n < 2; ++n)
#pragma unroll
      for (int i = 0; i < 16; ++i) acc[m][n][i] = 0.f;

  const int nt = K >> 5;
  // prologue: tiles 0,1 in flight; wait tile0 only (tile1's 4 stay in flight)
  stage(0, 0);
  if (nt > 1) { stage(1, 1); VMCNT(4); } else { VMCNT(0); }
  SBAR();

#define LDX(off) __builtin_bit_cast(bf16x8_t, *(const uint4*)(sp + (off)))
  int cur = 0, nxt = 1, nn = 2;
  for (int kt = 0; kt < nt; ++kt) {
    if (kt + 2 < nt) stage(kt + 2, nn);
    const ushort_t* sp = sm + cur * 8192;
    bf16x8_t af[2][2], bf[2][2];
#pragma unroll
    for (int m = 0; m < 2; ++m)
#pragma unroll
      for (int s = 0; s < 2; ++s) af[m][s] = LDX(offA[m][s]);
#pragma unroll
    for (int n = 0; n < 2; ++n)
#pragma unroll
      for (int s = 0; s < 2; ++s) bf[n][s] = LDX(offB[n][s]);
    __builtin_amdgcn_s_setprio(1);
#pragma unroll
    for (int s = 0; s < 2; ++s)
#pragma unroll
      for (int m = 0; m < 2; ++m)
#pragma unroll
        for (int n = 0; n < 2; ++n)
          acc[m][n] = __builtin_amdgcn_mfma_f32_32x32x16_bf16(
              af[m][s], bf[n][s], acc[m][n], 0, 0, 0);
    __builtin_amdgcn_s_setprio(0);
    if (kt + 1 < nt) {
      if (kt + 2 < nt) { VMCNT(4); }   // t+1 resident; t+2 stays in flight
      else             { VMCNT(0); }   // tail drain
    }
    SBAR();
    const int tmp = cur; cur = nxt; nxt = nn; nn = tmp;
  }
#undef LDX

  // ---- epilogue ----
  const long zC = (long)bz * sC;
#pragma unroll
  for (int m = 0; m < 2; ++m) {
    const int growb = bm + wr * 64 + m * 32;
    float part[16];
    if constexpr (EPI == 1) {
#pragma unroll
      for (int r = 0; r < 16; ++r) part[r] = 0.f;
    }
#pragma unroll
    for (int n = 0; n < 2; ++n) {
      const int gcol = bn + wc * 64 + n * 32 + l31;
      float bv_ = 0.f;
      if constexpr (HAS_BIAS) bv_ = bias[gcol];
#pragma unroll
      for (int r = 0; r < 16; ++r) {
        const int grow = growb + (r & 3) + 8 * (r >> 2) + 4 * kh;
        float v = acc[m][n][r] * alpha + bv_;
        if constexpr (EPI == 1) {
          const ushort_t pb = f2bf(__expf(v));
          ((ushort_t*)Cp)[zC + (long)grow * ldc + gcol] = pb;
          part[r] += bf2f(pb);
        } else if constexpr (EPI == 2) {
          v *= aux[bz * 2048 + grow];
          ((float*)Cp)[zC + (long)grow * ldc + gcol] = v;
        } else if constexpr (OUT_BF16) {
          ((ushort_t*)Cp)[zC + (long)grow * ldc + gcol] = f2bf(v);
        } else {
          ((float*)Cp)[zC + (long)grow * ldc + gcol] = v;
        }
      }
    }
    if constexpr (EPI == 1) {
      // col-reduce over the 32-lane group (rows are lane-invariant within it)
#pragma unroll
      for (int step = 1; step < 32; step <<= 1)
#pragma unroll
        for (int r = 0; r < 16; ++r) part[r] += __shfl_xor(part[r], step, 64);
      if (m == 0) {                    // zero LDS psum once, before first adds
        __syncthreads();
        float* pf = (float*)sm;
        if (tid < 128) pf[tid] = 0.f;
        __syncthreads();
      }
      if (l31 == 0) {
        float* pf = (float*)sm;
#pragma unroll
        for (int r = 0; r < 16; ++r) {
          const int rloc = wr * 64 + m * 32 + (r & 3) + 8 * (r >> 2) + 4 * kh;
          atomicAdd(&pf[rloc], part[r]);  // 2 adds/slot (wc=0,1): order-safe
        }
      }
    }
  }
  if constexpr (EPI == 1) {
    __syncthreads();
    if (tid < 128) {
      const float* pf = (const float*)sm;
      aux[(long)bx * 8192 + bz * 2048 + by * 128 + tid] = pf[tid];
    }
  }
}

// inv[r] = 1 / sum_k psumG[k][r],  16 col-chunks, 8192 rows
__global__ __launch_bounds__(256)
void invrow(const float* __restrict__ psumG, float* __restrict__ inv) {
  const int r = blockIdx.x * 256 + threadIdx.x;
  float s = 0.f;
#pragma unroll
  for (int k = 0; k < 16; ++k) s += psumG[(long)k * 8192 + r];
  inv[r] = 1.0f / s;
}

// fp32 -> bf16 bulk convert for x and y in one launch (8 elems/thread)
__global__ __launch_bounds__(256)
void conv2(const float* __restrict__ x, const float* __restrict__ y,
           ushort_t* __restrict__ xb, ushort_t* __restrict__ yb) {
  const int b = blockIdx.x;
  const float* in = (b < 4096) ? x : y;
  ushort_t* out = (b < 4096) ? xb : yb;
  const long i = (long)(b & 4095) * 256 + threadIdx.x;
  const float4 a = ((const float4*)in)[i * 2];
  const float4 c = ((const float4*)in)[i * 2 + 1];
  uint4 o;
  o.x = (unsigned)f2bf(a.x) | ((unsigned)f2bf(a.y) << 16);
  o.y = (unsigned)f2bf(a.z) | ((unsigned)f2bf(a.w) << 16);
  o.z = (unsigned)f2bf(c.x) | ((unsigned)f2bf(c.y) << 16);
  o.w = (unsigned)f2bf(c.z) | ((unsigned)f2bf(c.w) << 16);
  ((uint4*)out)[i] = o;
}

// Wt[n][k] = (bf16) W[k][n], D=1024, 3 weights in one launch (z selects)
__global__ __launch_bounds__(256)
void wtrans3(const float* __restrict__ W0, const float* __restrict__ W1,
             const float* __restrict__ W2, ushort_t* __restrict__ T0,
             ushort_t* __restrict__ T1, ushort_t* __restrict__ T2) {
  const float* W = (blockIdx.z == 0) ? W0 : (blockIdx.z == 1) ? W1 : W2;
  ushort_t* Wt = (blockIdx.z == 0) ? T0 : (blockIdx.z == 1) ? T1 : T2;
  __shared__ float tile[32][33];
  const int bx = blockIdx.x * 32;
  const int by = blockIdx.y * 32;
  const int t = threadIdx.x;
  const int c = t & 31, r0 = t >> 5;
#pragma unroll
  for (int i = 0; i < 4; ++i)
    tile[r0 + i * 8][c] = W[(long)(by + r0 + i * 8) * 1024 + bx + c];
  __syncthreads();
#pragma unroll
  for (int i = 0; i < 4; ++i)
    Wt[(long)(bx + r0 + i * 8) * 1024 + by + c] = f2bf(tile[c][r0 + i * 8]);
}

__global__ __launch_bounds__(256)
void bconcat(const float* __restrict__ a, const float* __restrict__ b,
             float* __restrict__ o) {
  const int i = blockIdx.x * 256 + threadIdx.x;
  o[i] = (i < 1024) ? a[i] : b[i - 1024];
}

// bf16 transpose with strides: out[c][r] = in[r][c], 64x64 tiles per batch
__global__ __launch_bounds__(256)
void transpose_bf16(const ushort_t* __restrict__ in, ushort_t* __restrict__ out,
                    int ld_in, int ld_out, long in_bs, long out_bs) {
  __shared__ ushort_t tt[64][65];
  in += (long)blockIdx.z * in_bs;
  out += (long)blockIdx.z * out_bs;
  const int r0 = blockIdx.y * 64, c0 = blockIdx.x * 64;
  const int tc = threadIdx.x & 31;
  const int tr = threadIdx.x >> 5;
#pragma unroll
  for (int i = 0; i < 8; ++i) {
    const unsigned v = *(const unsigned*)(in + (long)(r0 + tr + 8 * i) * ld_in + c0 + tc * 2);
    tt[tr + 8 * i][tc * 2] = (ushort_t)(v & 0xffff);
    tt[tr + 8 * i][tc * 2 + 1] = (ushort_t)(v >> 16);
  }
  __syncthreads();
#pragma unroll
  for (int i = 0; i < 8; ++i) {
    const unsigned v = (unsigned)tt[tc * 2][tr + 8 * i] |
                       ((unsigned)tt[tc * 2 + 1][tr + 8 * i] << 16);
    *(unsigned*)(out + (long)(c0 + tr + 8 * i) * ld_out + r0 + tc * 2) = v;
  }
}

extern "C" void kernel_launch(void* const* d_in, const int* in_sizes, int n_in,
                              void* d_out, int out_size, void* d_ws, size_t ws_size,
                              hipStream_t stream) {
  const float* x  = (const float*)d_in[0];
  const float* y  = (const float*)d_in[1];
  const float* Wq = (const float*)d_in[2];
  const float* bq = (const float*)d_in[3];
  const float* Wk = (const float*)d_in[4];
  const float* bk = (const float*)d_in[5];
  const float* Wv = (const float*)d_in[6];
  const float* bv = (const float*)d_in[7];
  float* out = (float*)d_out;

  const int D = 1024;
  const long MB_ = 1l << 20;

  ushort_t* ws  = (ushort_t*)d_ws;
  ushort_t* Wqt = ws;                    // [1024][1024], 1M
  ushort_t* Wkv = ws + 1 * MB_;          // Wkt||Wvt = [2048][1024], 2M
  ushort_t* Wvt = ws + 2 * MB_;
  ushort_t* Qb  = ws + 3 * MB_;          // [8192][1024], 8M
  ushort_t* KV  = ws + 11 * MB_;         // [8192][2048], 16M
  ushort_t* yb  = ws + 27 * MB_;         // [8192][1024], 8M
  ushort_t* Vt  = ws + 27 * MB_;         // alias yb: [B][1024][2048]
  ushort_t* xb  = ws + 35 * MB_;         // [8192][1024], 8M
  ushort_t* Sb  = ws + 35 * MB_;         // alias xb: [B][2048][2048], 16M
  float*    bkv = (float*)(ws + 51 * MB_);           // [2048] f32
  float*    psumG = (float*)(ws + 51 * MB_ + 8192);  // [16][8192] f32, 512KB
  float*    inv = psumG + 16 * 8192;                 // [8192] f32

  dim3 blk(256);

  conv2<<<dim3(8192), blk, 0, stream>>>(x, y, xb, yb);
  wtrans3<<<dim3(32, 32, 3), blk, 0, stream>>>(Wq, Wk, Wv, Wqt, Wkv, Wvt);
  bconcat<<<dim3(8), blk, 0, stream>>>(bk, bv, bkv);

  // Q = xb @ Wqt^T + bq -> [8192][1024]; grid 8x64 = 512
  gemm32<0, true, true><<<dim3(512), blk, 0, stream>>>(
      xb, Wqt, Qb, bq, nullptr, 8, 64, D, D, D, D, 0, 0, 0, 1.0f);
  // KV = yb @ Wkv^T + bkv -> [8192][2048]; grid 16x64 = 1024
  gemm32<0, true, true><<<dim3(1024), blk, 0, stream>>>(
      yb, Wkv, KV, bkv, nullptr, 16, 64, D, D, D, 2048, 0, 0, 0, 1.0f);
  // Vt[b][d][t] = KV[b*2048+t][1024+d]
  transpose_bf16<<<dim3(16, 32, 4), blk, 0, stream>>>(
      KV + 1024, Vt, 2048, 2048, 2048l * 2048, 1024l * 2048);

  // P' = exp((Q K^T)/32) -> bf16 [B][2048][2048] + per-(colblock,row) sums
  gemm32<1, true, false><<<dim3(1024), blk, 0, stream>>>(
      Qb, KV, Sb, nullptr, psumG, 16, 16, D, D, 2048, 2048,
      2048l * 1024, 2048l * 2048, 2048l * 2048, 0.03125f);

  invrow<<<dim3(32), blk, 0, stream>>>(psumG, inv);

  // out = (P' @ V) * inv[row]  (NT vs Vt [1024][2048]) -> fp32
  gemm32<2, false, false><<<dim3(512), blk, 0, stream>>>(
      Sb, Vt, out, nullptr, inv, 8, 16, 2048, 2048, 2048, D,
      2048l * 2048, 1024l * 2048, 2048l * 1024, 1.0f);
}